// Round 5
// baseline (252.653 us; speedup 1.0000x reference)
//
#include <hip/hip_runtime.h>
#include <hip/hip_bf16.h>
#include <math.h>

#define HID 512
#define HEADS 4
#define OUTF 128

typedef __attribute__((ext_vector_type(8))) _Float16 f16x8_t;   // 8 f16 in 4 VGPRs
typedef __attribute__((ext_vector_type(4))) _Float16 f16x4_t;
typedef __attribute__((ext_vector_type(4))) float f32x4_t;

// ---------------------------------------------------------------------------
// helpers
// ---------------------------------------------------------------------------
__device__ __forceinline__ void gl_lds16(const void* g, void* l) {
    __builtin_amdgcn_global_load_lds(
        (const __attribute__((address_space(1))) void*)g,
        (__attribute__((address_space(3))) void*)l, 16, 0, 0);
}

// stage a [ROWS rows][32 f16] plane into LDS with XOR-chunk swizzle
// (chunk ^= (row>>1)&3). LDS byte gci*16 holds row (gci>>2), logical chunk
// (gci&3) ^ ((row>>1)&3). Read side measured conflict-free
// (SQ_LDS_BANK_CONFLICT=0 across all rounds).
template<int ROWS, int THREADS>
__device__ __forceinline__ void stage_f16(const _Float16* g, int strideE,
    int rbase, int rmax, char* plane, int tid)
{
    constexpr int CH = ROWS * 4;               // 16B chunks in the plane
#pragma unroll
    for (int j = 0; j < CH / THREADS; ++j) {
        int gci = j * THREADS + tid;
        int r = gci >> 2, c = gci & 3;
        int rg = rbase + r; if (rg > rmax) rg = rmax;
        const char* s = (const char*)(g + (size_t)rg * strideE) + ((c ^ ((r >> 1) & 3)) << 4);
        char* d = plane + (j * THREADS + (tid & ~63)) * 16;   // wave-uniform base
        gl_lds16(s, d);
    }
}

// fp32 A staging (fused conv16): same LDS image as stage_f16<128>, sourced
// from 32B of fp32 per chunk. Split into issue-early load (T14) and
// cvt+ds_write after the MFMA block.
template<int THREADS>
__device__ __forceinline__ void a32_load(const float* g, int strideE,
    int rbase, int rmax, int tid, int kbase, float4* v)
{
#pragma unroll
    for (int j = 0; j < 512 / THREADS; ++j) {
        int gci = j * THREADS + tid;
        int r = gci >> 2, c = gci & 3;
        int rg = rbase + r; if (rg > rmax) rg = rmax;
        const float* s = g + (size_t)rg * strideE + kbase + ((c ^ ((r >> 1) & 3)) << 3);
        v[j * 2]     = *(const float4*)s;
        v[j * 2 + 1] = *(const float4*)(s + 4);
    }
}
template<int THREADS>
__device__ __forceinline__ void a32_write(char* plane, int tid, const float4* v)
{
#pragma unroll
    for (int j = 0; j < 512 / THREADS; ++j) {
        const float4 a = v[j * 2], b = v[j * 2 + 1];
        f16x8_t o;
        o[0] = (_Float16)a.x; o[1] = (_Float16)a.y;
        o[2] = (_Float16)a.z; o[3] = (_Float16)a.w;
        o[4] = (_Float16)b.x; o[5] = (_Float16)b.y;
        o[6] = (_Float16)b.z; o[7] = (_Float16)b.w;
        *(f16x8_t*)(plane + (j * THREADS + tid) * 16) = o;
    }
}

// ---------------------------------------------------------------------------
// W prep: transpose [K][NC] fp32 -> [NC][K] fp16
// ---------------------------------------------------------------------------
__global__ __launch_bounds__(256) void prep_w(const float* __restrict__ W,
    _Float16* __restrict__ Wt, int K, int NC)
{
    __shared__ float tile[32][33];
    const int k0 = blockIdx.x * 32, n0 = blockIdx.y * 32;
    const int t = threadIdx.x;
    {
        int r = t >> 3, c4 = (t & 7) * 4;
        float4 v = *(const float4*)&W[(size_t)(k0 + r) * NC + n0 + c4];
        tile[r][c4] = v.x; tile[r][c4 + 1] = v.y;
        tile[r][c4 + 2] = v.z; tile[r][c4 + 3] = v.w;
    }
    __syncthreads();
    int n = t >> 3, kc = (t & 7) * 4;
#pragma unroll
    for (int i = 0; i < 4; ++i)
        Wt[(size_t)(n0 + n) * K + k0 + kc + i] = (_Float16)tile[kc + i][n];
}

// ---------------------------------------------------------------------------
// fp16 MFMA GEMM: C[M][NCOL] = A[M][K] @ B[K][NCOL].
// Tile 128 x BN, BK=32. BN=256: 8 waves (2x4 grid); BN=128: 4 waves (2x2).
// Every wave keeps the proven 64x64 tile (acc 4x4 frags, swizzled b128 reads).
// Double-buffered K-loop, one barrier per K-step.
// STAGING-DELIVERY MODEL (rounds 1-4): dur ~ staged_bytes / 6.5 TB/s.
// BN=256 halves A duplication (2 col-tiles/row instead of 4): L1 staged
// 602 -> 402 MB. XCD swizzle keeps a row's col-pair on one XCD (L2-served).
// A32 1: A is fp32, reg-staged + converted (conv16 fused; saves 153 MB HBM).
// EPI: fused bias+ELU. OUT16: f16 C. ELER: emit el/er (BN/128 heads per tile).
// ---------------------------------------------------------------------------
template<int EPI, int OUT16, int ELER, int A32, int BN>
__global__ __launch_bounds__(BN * 2, BN == 256 ? 4 : 3) void gemm_f16(
    const void* __restrict__ Ap, const _Float16* __restrict__ Bt,
    const float* __restrict__ bias,
    const float* __restrict__ attl, const float* __restrict__ attr,
    float* __restrict__ elp, float* __restrict__ erp,
    void* __restrict__ Cout, int M, int K, int NCOL, int ldC,
    int ncolT, int nwg)
{
    constexpr int THREADS = BN * 2;
    constexpr int NWN = BN / 64;            // wave-grid cols (2 or 4)
    constexpr int ABUF = 8192;              // A plane bytes (128 x 64B)
    constexpr int BBUF = BN * 64;           // B plane bytes (BN x 64B)
    constexpr int HBUF = ABUF + BBUF;
    __shared__ char lds[2 * HBUF];
    const _Float16* Af   = (const _Float16*)Ap;
    const float*    Af32 = (const float*)Ap;
    const int tid = threadIdx.x;
    const int wave = tid >> 6, lane = tid & 63;
    const int wm = wave / NWN, wn = wave % NWN;
    // bijective XCD swizzle: each XCD gets a contiguous logical chunk
    const int b = blockIdx.x;
    const int q = nwg >> 3, rr = nwg & 7;
    const int xcd = b & 7, ib = b >> 3;
    const int logical = (xcd < rr ? xcd * (q + 1) : rr * (q + 1) + (xcd - rr) * q) + ib;
    const int bm = (logical / ncolT) * 128, bcol = logical % ncolT;
    const int bn = bcol * BN;
    const int l15 = lane & 15, l4 = lane >> 4;
    const int swz = (l15 >> 1) & 3;

    f32x4_t acc[4][4];
#pragma unroll
    for (int i = 0; i < 4; ++i)
#pragma unroll
        for (int j = 0; j < 4; ++j) acc[i][j] = (f32x4_t){0.f, 0.f, 0.f, 0.f};

    const int nt = K >> 5;                         // BK = 32
    float4 pre[4];
    if (A32) {
        a32_load<THREADS>(Af32, K, bm, M - 1, tid, 0, pre);
        a32_write<THREADS>(lds, tid, pre);
    } else {
        stage_f16<128, THREADS>(Af, K, bm, M - 1, lds, tid);
    }
    stage_f16<BN, THREADS>(Bt, K, bn, NCOL - 1, lds + ABUF, tid);
    __syncthreads();

    for (int t = 0; t < nt; ++t) {
        char* AH = lds + (t & 1) * HBUF;
        char* BH = AH + ABUF;
        char* AHn = lds + ((t + 1) & 1) * HBUF;
        if (t + 1 < nt) {
            if (A32) a32_load<THREADS>(Af32, K, bm, M - 1, tid, (t + 1) * 32, pre);
            else     stage_f16<128, THREADS>(Af + (t + 1) * 32, K, bm, M - 1, AHn, tid);
            stage_f16<BN, THREADS>(Bt + (t + 1) * 32, K, bn, NCOL - 1, AHn + ABUF, tid);
        }
        f16x8_t fa[4], fb[4];
#pragma unroll
        for (int mf = 0; mf < 4; ++mf) {
            int row = wm * 64 + mf * 16 + l15;
            fa[mf] = *(const f16x8_t*)(AH + row * 64 + ((l4 ^ swz) << 4));
        }
#pragma unroll
        for (int nf = 0; nf < 4; ++nf) {
            int rn = wn * 64 + nf * 16 + l15;
            fb[nf] = *(const f16x8_t*)(BH + rn * 64 + ((l4 ^ swz) << 4));
        }
#pragma unroll
        for (int mf = 0; mf < 4; ++mf)
#pragma unroll
            for (int nf = 0; nf < 4; ++nf)
                acc[mf][nf] = __builtin_amdgcn_mfma_f32_16x16x32_f16(fa[mf], fb[nf], acc[mf][nf], 0, 0, 0);
        if (A32 && t + 1 < nt) a32_write<THREADS>(AHn, tid, pre);
        __syncthreads();
    }
    // epilogue: C/D layout col=lane&15, row=(lane>>4)*4+reg
#pragma unroll
    for (int mf = 0; mf < 4; ++mf) {
        int rbase = bm + wm * 64 + mf * 16 + l4 * 4;
#pragma unroll
        for (int nf = 0; nf < 4; ++nf) {
            int col = bn + wn * 64 + nf * 16 + l15;
            if (col >= NCOL) continue;
#pragma unroll
            for (int r = 0; r < 4; ++r) {
                int row = rbase + r;
                if (row < M) {
                    float v = acc[mf][nf][r];
                    if (EPI) {
                        v += bias[col];
                        v = v > 0.f ? v : (expf(v) - 1.f);
                    }
                    if (OUT16) ((_Float16*)Cout)[(size_t)row * ldC + col] = (_Float16)v;
                    else       ((float*)Cout)[(size_t)row * ldC + col] = v;
                }
            }
        }
    }
    if (ELER) {
        constexpr int HPT = BN / 128;          // heads per tile (1 or 2)
        const int head = bcol * HPT + (wn >> 1);
        float alv[4], arv[4];
#pragma unroll
        for (int nf = 0; nf < 4; ++nf) {
            int cl = (wn & 1) * 64 + nf * 16 + l15;  // col within head (0..127)
            alv[nf] = attl[head * OUTF + cl];
            arv[nf] = attr[head * OUTF + cl];
        }
        float pel[4][4], perr[4][4];
#pragma unroll
        for (int mf = 0; mf < 4; ++mf)
#pragma unroll
            for (int r = 0; r < 4; ++r) {
                float se = 0.f, sr = 0.f;
#pragma unroll
                for (int nf = 0; nf < 4; ++nf) {
                    se = fmaf(acc[mf][nf][r], alv[nf], se);
                    sr = fmaf(acc[mf][nf][r], arv[nf], sr);
                }
                pel[mf][r] = se; perr[mf][r] = sr;
            }
        // reduce across the 16-lane column group
#pragma unroll
        for (int off = 1; off < 16; off <<= 1)
#pragma unroll
            for (int mf = 0; mf < 4; ++mf)
#pragma unroll
                for (int r = 0; r < 4; ++r) {
                    pel[mf][r]  += __shfl_xor(pel[mf][r],  off);
                    perr[mf][r] += __shfl_xor(perr[mf][r], off);
                }
        __syncthreads();
        float* red = (float*)lds;              // [128][NWN] el, then er
        if (l15 == 0) {
#pragma unroll
            for (int mf = 0; mf < 4; ++mf)
#pragma unroll
                for (int r = 0; r < 4; ++r) {
                    int rl = wm * 64 + mf * 16 + l4 * 4 + r;
                    red[rl * NWN + wn]             = pel[mf][r];
                    red[128 * NWN + rl * NWN + wn] = perr[mf][r];
                }
        }
        __syncthreads();
        if (tid < 128 * HPT) {
            int rl = tid & 127;
            int hh = tid >> 7;                 // head-within-tile
            int row = bm + rl;
            if (row < M) {
                float es = red[rl * NWN + hh * 2] + red[rl * NWN + hh * 2 + 1];
                float rs = red[128 * NWN + rl * NWN + hh * 2]
                         + red[128 * NWN + rl * NWN + hh * 2 + 1];
                elp[row * HEADS + bcol * HPT + hh] = es;
                erp[row * HEADS + bcol * HPT + hh] = rs;
            }
        }
    }
}

// --------------------------- CSR build -------------------------------------
__global__ void hist_kernel(const int* __restrict__ dst, int* __restrict__ deg, int E)
{
    int e = blockIdx.x * 256 + threadIdx.x;
    if (e < E) atomicAdd(&deg[dst[e]], 1);
}

__global__ __launch_bounds__(256) void scan1_kernel(const int* __restrict__ deg,
    int* __restrict__ offs, int* __restrict__ bsum, int N)
{
    __shared__ int buf[256];
    int tid = threadIdx.x;
    int i = blockIdx.x * 256 + tid;
    int v = (i < N) ? deg[i] : 0;
    buf[tid] = v;
    __syncthreads();
#pragma unroll
    for (int off = 1; off < 256; off <<= 1) {
        int t = (tid >= off) ? buf[tid - off] : 0;
        __syncthreads();
        buf[tid] += t;
        __syncthreads();
    }
    if (i < N) offs[i] = buf[tid] - v;
    if (tid == 255) bsum[blockIdx.x] = buf[255];
}

__global__ void scan2_kernel(int* __restrict__ bsum, int nb)
{
    if (threadIdx.x == 0) {
        int acc = 0;
        for (int b = 0; b < nb; ++b) { int t = bsum[b]; bsum[b] = acc; acc += t; }
        bsum[nb] = acc;
    }
}

__global__ void scan3_kernel(int* __restrict__ offs, const int* __restrict__ bsum,
                             int N, int nb)
{
    int i = blockIdx.x * 256 + threadIdx.x;
    if (i < N) offs[i] += bsum[blockIdx.x];
    if (i == 0) offs[N] = bsum[nb];
}

// fill: write src-id directly into the node's slot (psrc = src[csr[...]])
__global__ void fill_kernel(const int* __restrict__ srcv, const int* __restrict__ dstv,
    const int* __restrict__ offs, int* __restrict__ cursor,
    int* __restrict__ psrc, int E)
{
    int e = blockIdx.x * 256 + threadIdx.x;
    if (e < E) {
        int d = dstv[e];
        int p = atomicAdd(&cursor[d], 1);
        psrc[offs[d] + p] = srcv[e];
    }
}

// ------ aggregation v5: barrier-free shuffle-broadcast, 4 nodes/block ------
// One wave per node (4 waves / 256-thr block). Chunk = 32 edges staged in
// registers: lane L stages edge (L&31) for head-pair (L>>5) -- one float2 el
// gather + 2 exp. Weights and source ids broadcast via __shfl (wave lockstep
// => no LDS, no __syncthreads). BW-bound at the gather delivery ceiling.
__global__ __launch_bounds__(256) void aggregate_kernel(const _Float16* __restrict__ h,
    const int* __restrict__ offs, const int* __restrict__ psrc,
    const float* __restrict__ el, const float* __restrict__ er,
    const float* __restrict__ bias, _Float16* __restrict__ xo, int N)
{
    const int n = blockIdx.x * 4 + (threadIdx.x >> 6);
    if (n >= N) return;
    const int lane = threadIdx.x & 63;
    const int c = lane * 8;
    const int head = lane >> 4;           // reader head (0..3)
    const int hp = lane >> 5;             // staged head-pair (0:h01, 1:h23)
    const int e31 = lane & 31;
    const int sbase = (head >> 1) << 5;   // source-lane base for my head-pair
    const int hsel = head & 1;

    const float2 er2 = *(const float2*)&er[n * HEADS + hp * 2];

    float acc[8];
#pragma unroll
    for (int k = 0; k < 8; ++k) acc[k] = 0.f;
    float ws = 0.f;

    const int beg = offs[n], end = offs[n + 1];
    for (int base = beg; base < end; base += 32) {
        const int cnt = min(32, end - base);
        int idx = base + e31;
        if (e31 >= cnt) idx = beg;        // safe dummy (deg >= 1: self loop)
        const int s = psrc[idx];
        const float2 lv = *(const float2*)&el[s * HEADS + hp * 2];
        float x0 = lv.x + er2.x; x0 = x0 > 0.f ? x0 : 0.2f * x0;
        float x1 = lv.y + er2.y; x1 = x1 > 0.f ? x1 : 0.2f * x1;
        const float wa = expf(x0);        // weight for head hp*2
        const float wb = expf(x1);        // weight for head hp*2+1

        int j = 0;
        for (; j + 4 <= cnt; j += 4) {
            int s0 = __shfl(s, j);     int s1 = __shfl(s, j + 1);
            int s2 = __shfl(s, j + 2); int s3 = __shfl(s, j + 3);
            float a0 = __shfl(wa, sbase + j),     b0 = __shfl(wb, sbase + j);
            float a1 = __shfl(wa, sbase + j + 1), b1 = __shfl(wb, sbase + j + 1);
            float a2 = __shfl(wa, sbase + j + 2), b2 = __shfl(wb, sbase + j + 2);
            float a3 = __shfl(wa, sbase + j + 3), b3 = __shfl(wb, sbase + j + 3);
            float w0 = hsel ? b0 : a0;
            float w1 = hsel ? b1 : a1;
            float w2 = hsel ? b2 : a2;
            float w3 = hsel ? b3 : a3;
            f16x8_t v0 = *(const f16x8_t*)&h[(size_t)s0 * HID + c];
            f16x8_t v1 = *(const f16x8_t*)&h[(size_t)s1 * HID + c];
            f16x8_t v2 = *(const f16x8_t*)&h[(size_t)s2 * HID + c];
            f16x8_t v3 = *(const f16x8_t*)&h[(size_t)s3 * HID + c];
#pragma unroll
            for (int k = 0; k < 8; ++k) {
                acc[k] = fmaf(w0, (float)v0[k], acc[k]);
                acc[k] = fmaf(w1, (float)v1[k], acc[k]);
                acc[k] = fmaf(w2, (float)v2[k], acc[k]);
                acc[k] = fmaf(w3, (float)v3[k], acc[k]);
            }
            ws += w0 + w1 + w2 + w3;
        }
        for (; j < cnt; ++j) {
            int s0 = __shfl(s, j);
            float a0 = __shfl(wa, sbase + j), b0 = __shfl(wb, sbase + j);
            float w0 = hsel ? b0 : a0;
            f16x8_t v0 = *(const f16x8_t*)&h[(size_t)s0 * HID + c];
#pragma unroll
            for (int k = 0; k < 8; ++k) acc[k] = fmaf(w0, (float)v0[k], acc[k]);
            ws += w0;
        }
    }
    float inv = 1.f / ws;
    float4 b0v = *(const float4*)&bias[c];
    float4 b1v = *(const float4*)&bias[c + 4];
    float bb[8] = {b0v.x, b0v.y, b0v.z, b0v.w, b1v.x, b1v.y, b1v.z, b1v.w};
    f16x8_t ov;
#pragma unroll
    for (int k = 0; k < 8; ++k) {
        float r = acc[k] * inv + bb[k];
        r = r > 0.f ? r : (expf(r) - 1.f);
        ov[k] = (_Float16)r;
    }
    *(f16x8_t*)&xo[(size_t)n * HID + c] = ov;
}

// ---------------------------------------------------------------------------
extern "C" void kernel_launch(void* const* d_in, const int* in_sizes, int n_in,
                              void* d_out, int out_size, void* d_ws, size_t ws_size,
                              hipStream_t stream)
{
    const float* feature = (const float*)d_in[0];
    const float* W1  = (const float*)d_in[1];
    const float* al1 = (const float*)d_in[2];
    const float* ar1 = (const float*)d_in[3];
    const float* b1  = (const float*)d_in[4];
    const float* W2  = (const float*)d_in[5];
    const float* al2 = (const float*)d_in[6];
    const float* ar2 = (const float*)d_in[7];
    const float* b2  = (const float*)d_in[8];
    const float* Wfc = (const float*)d_in[9];
    const float* bfc = (const float*)d_in[10];
    const int* src = (const int*)d_in[11];
    const int* dst = (const int*)d_in[12];
    const int N = in_sizes[0] / 1280;
    const int E = in_sizes[11];
    const int nb = (N + 255) / 256;
    float* out = (float*)d_out;

    char* ws = (char*)d_ws;
    size_t off = 0;
    auto alloc = [&](size_t bytes) {
        void* p = ws + off;
        off += (bytes + 255) & ~(size_t)255;
        return p;
    };
    int* deg    = (int*)alloc((size_t)N * 4);
    int* cursor = (int*)alloc((size_t)N * 4);
    int* offs   = (int*)alloc((size_t)(N + 1) * 4);
    int* bsum   = (int*)alloc((size_t)(nb + 1) * 4);
    float* el   = (float*)alloc((size_t)N * HEADS * 4);
    float* er   = (float*)alloc((size_t)N * HEADS * 4);
    int* psrc   = (int*)alloc((size_t)E * 4);
    _Float16* hbuf  = (_Float16*)alloc((size_t)N * HID * 2);
    _Float16* xh    = (_Float16*)alloc((size_t)N * HID * 2);
    _Float16* W1t   = (_Float16*)alloc((size_t)HID * 1280 * 2);
    _Float16* W2t   = (_Float16*)alloc((size_t)HID * HID * 2);
    _Float16* Wft   = (_Float16*)alloc((size_t)64 * HID * 2);

    // CSR build (psrc written directly)
    hipMemsetAsync(deg, 0, (size_t)N * 4, stream);
    hipMemsetAsync(cursor, 0, (size_t)N * 4, stream);
    hist_kernel<<<(E + 255) / 256, 256, 0, stream>>>(dst, deg, E);
    scan1_kernel<<<nb, 256, 0, stream>>>(deg, offs, bsum, N);
    scan2_kernel<<<1, 64, 0, stream>>>(bsum, nb);
    scan3_kernel<<<nb, 256, 0, stream>>>(offs, bsum, N, nb);
    fill_kernel<<<(E + 255) / 256, 256, 0, stream>>>(src, dst, offs, cursor, psrc, E);

    // W prep (fp16, transposed). conv16 stays fused into the L1 GEMM (A32=1).
    prep_w<<<dim3(1280 / 32, HID / 32), 256, 0, stream>>>(W1, W1t, 1280, HID);
    prep_w<<<dim3(HID / 32, HID / 32), 256, 0, stream>>>(W2, W2t, HID, HID);
    prep_w<<<dim3(HID / 32, 64 / 32), 256, 0, stream>>>(Wfc, Wft, HID, 64);

    const int nrowT = (N + 127) / 128;
    const int nwgG = nrowT * 2;             // 2 col tiles of 256
    const int nwgF = nrowT;                 // 1 col tile (NCOL=64)
    const int aggB = (N + 3) / 4;

    // ---- layer 1 (GEMM on fp32 feature + fused el/er), 128x256 tiles ----
    gemm_f16<0, 1, 1, 1, 256><<<nwgG, 512, 0, stream>>>(feature, W1t, nullptr,
                                                        al1, ar1, el, er,
                                                        hbuf, N, 1280, HID, HID,
                                                        2, nwgG);
    aggregate_kernel<<<aggB, 256, 0, stream>>>(hbuf, offs, psrc, el, er, b1, xh, N);

    // ---- layer 2, 128x256 tiles ----
    gemm_f16<0, 1, 1, 0, 256><<<nwgG, 512, 0, stream>>>(xh, W2t, nullptr,
                                                        al2, ar2, el, er,
                                                        hbuf, N, HID, HID, HID,
                                                        2, nwgG);
    aggregate_kernel<<<aggB, 256, 0, stream>>>(hbuf, offs, psrc, el, er, b2, xh, N);

    // ---- fc: MFMA GEMM with fused bias+ELU, fp32 out (128-wide path) ----
    gemm_f16<1, 0, 0, 0, 128><<<nwgF, 256, 0, stream>>>(xh, Wft, bfc,
                                                        nullptr, nullptr, nullptr, nullptr,
                                                        out, N, HID, 64, 64,
                                                        1, nwgF);
}

// Round 6
// 245.623 us; speedup vs baseline: 1.0286x; 1.0286x over previous
//
#include <hip/hip_runtime.h>
#include <hip/hip_bf16.h>
#include <math.h>

#define HID 512
#define HEADS 4
#define OUTF 128

typedef __attribute__((ext_vector_type(8))) _Float16 f16x8_t;   // 8 f16 in 4 VGPRs
typedef __attribute__((ext_vector_type(4))) _Float16 f16x4_t;
typedef __attribute__((ext_vector_type(4))) float f32x4_t;

// ---------------------------------------------------------------------------
// helpers
// ---------------------------------------------------------------------------
__device__ __forceinline__ void gl_lds16(const void* g, void* l) {
    __builtin_amdgcn_global_load_lds(
        (const __attribute__((address_space(1))) void*)g,
        (__attribute__((address_space(3))) void*)l, 16, 0, 0);
}

// stage a [128 rows][32 f16] plane into LDS with XOR-chunk swizzle
// (chunk ^= (row>>1)&3), 256 threads: 2 chunks (2 gl_lds instrs) per thread.
// Read side measured conflict-free (SQ_LDS_BANK_CONFLICT=0 across rounds).
__device__ __forceinline__ void stage_plane32(const _Float16* g, int strideE,
    int rbase, int rmax, char* plane, int tid)
{
#pragma unroll
    for (int j = 0; j < 2; ++j) {
        int gci = j * 256 + tid;             // 0..511
        int r = gci >> 2, c = gci & 3;
        int rg = rbase + r; if (rg > rmax) rg = rmax;
        const char* s = (const char*)(g + (size_t)rg * strideE) + ((c ^ ((r >> 1) & 3)) << 4);
        char* d = plane + (j * 256 + (tid & ~63)) * 16;   // wave-uniform base
        gl_lds16(s, d);
    }
}

// fp32 A staging (fused conv16): same LDS image as stage_plane32, sourced
// from 32B of fp32 per chunk. Issue-early load, cvt+ds_write after MFMA (T14).
__device__ __forceinline__ void a32_load(const float* g, int strideE,
    int rbase, int rmax, int tid, int kbase, float4* v)
{
#pragma unroll
    for (int j = 0; j < 2; ++j) {
        int gci = j * 256 + tid;
        int r = gci >> 2, c = gci & 3;
        int rg = rbase + r; if (rg > rmax) rg = rmax;
        const float* s = g + (size_t)rg * strideE + kbase + ((c ^ ((r >> 1) & 3)) << 3);
        v[j * 2]     = *(const float4*)s;
        v[j * 2 + 1] = *(const float4*)(s + 4);
    }
}
__device__ __forceinline__ void a32_write(char* plane, int tid, const float4* v)
{
#pragma unroll
    for (int j = 0; j < 2; ++j) {
        const float4 a = v[j * 2], b = v[j * 2 + 1];
        f16x8_t o;
        o[0] = (_Float16)a.x; o[1] = (_Float16)a.y;
        o[2] = (_Float16)a.z; o[3] = (_Float16)a.w;
        o[4] = (_Float16)b.x; o[5] = (_Float16)b.y;
        o[6] = (_Float16)b.z; o[7] = (_Float16)b.w;
        *(f16x8_t*)(plane + (j * 256 + tid) * 16) = o;
    }
}

// ---------------------------------------------------------------------------
// W prep: transpose [K][NC] fp32 -> [NC][K] fp16
// ---------------------------------------------------------------------------
__global__ __launch_bounds__(256) void prep_w(const float* __restrict__ W,
    _Float16* __restrict__ Wt, int K, int NC)
{
    __shared__ float tile[32][33];
    const int k0 = blockIdx.x * 32, n0 = blockIdx.y * 32;
    const int t = threadIdx.x;
    {
        int r = t >> 3, c4 = (t & 7) * 4;
        float4 v = *(const float4*)&W[(size_t)(k0 + r) * NC + n0 + c4];
        tile[r][c4] = v.x; tile[r][c4 + 1] = v.y;
        tile[r][c4 + 2] = v.z; tile[r][c4 + 3] = v.w;
    }
    __syncthreads();
    int n = t >> 3, kc = (t & 7) * 4;
#pragma unroll
    for (int i = 0; i < 4; ++i)
        Wt[(size_t)(n0 + n) * K + k0 + kc + i] = (_Float16)tile[kc + i][n];
}

// ---------------------------------------------------------------------------
// fp16 MFMA GEMM: C[M][NCOL] = A[M][K] @ B[K][NCOL].
// 4 waves (256 thr), tile 128x128, BK=32, wave tile 64x64 (acc 4x4 frags).
// PIPELINED K-loop (T3/T4): A double-buffered, B TRIPLE-buffered; each iter
// issues B(t+2); pre-barrier wait is s_waitcnt vmcnt(2) (drains B(t+1)/A(t+1),
// leaves B(t+2) in flight across the raw s_barrier). This removes the
// vmcnt(0)-drain-per-step that capped per-CU staging delivery at ~13 B/cyc
// (rounds 1-5 post-mortem). LDS 40 KB -> 4 blocks/CU.
// Invariant: a buffer is read only after a barrier every wave entered with
// that buffer's loads drained (vmcnt(2) leaves only the t+2 stage in flight;
// planes t, t+1, t+2 are disjoint mod 3).
// A32 1: A is fp32, reg-staged + converted (conv16 fused).
// EPI: fused bias+ELU. OUT16: f16 C. ELER: emit el/er (head=col tile).
// ---------------------------------------------------------------------------
template<int EPI, int OUT16, int ELER, int A32>
__global__ __launch_bounds__(256, 4) void gemm_f16(
    const void* __restrict__ Ap, const _Float16* __restrict__ Bt,
    const float* __restrict__ bias,
    const float* __restrict__ attl, const float* __restrict__ attr,
    float* __restrict__ elp, float* __restrict__ erp,
    void* __restrict__ Cout, int M, int K, int NCOL, int ldC,
    int ncolT, int nwg)
{
    __shared__ char lds[40960];
    char* const abase = lds;            // 2 x 8192 (A double buffer)
    char* const bbase = lds + 16384;    // 3 x 8192 (B triple buffer)
    const _Float16* Af   = (const _Float16*)Ap;
    const float*    Af32 = (const float*)Ap;
    const int tid = threadIdx.x;
    const int wave = tid >> 6, lane = tid & 63;
    const int wm = wave >> 1, wn = wave & 1;      // 2 x 2 wave grid
    // bijective XCD swizzle: each XCD gets a contiguous logical chunk
    const int b = blockIdx.x;
    const int q = nwg >> 3, rr = nwg & 7;
    const int xcd = b & 7, ib = b >> 3;
    const int logical = (xcd < rr ? xcd * (q + 1) : rr * (q + 1) + (xcd - rr) * q) + ib;
    const int bm = (logical / ncolT) * 128, bcol = logical % ncolT;
    const int bn = bcol * 128;
    const int l15 = lane & 15, l4 = lane >> 4;
    const int swz = (l15 >> 1) & 3;

    f32x4_t acc[4][4];
#pragma unroll
    for (int i = 0; i < 4; ++i)
#pragma unroll
        for (int j = 0; j < 4; ++j) acc[i][j] = (f32x4_t){0.f, 0.f, 0.f, 0.f};

    const int nt = K >> 5;                         // BK = 32
    float4 pre[4];
    // prologue: stage A(0), B(0), B(1); drain all but B(1)
    if (A32) {
        a32_load(Af32, K, bm, M - 1, tid, 0, pre);
        a32_write(abase, tid, pre);
    } else {
        stage_plane32(Af, K, bm, M - 1, abase, tid);
    }
    stage_plane32(Bt, K, bn, NCOL - 1, bbase, tid);
    if (nt > 1) {
        stage_plane32(Bt + 32, K, bn, NCOL - 1, bbase + 8192, tid);
        asm volatile("s_waitcnt vmcnt(2) lgkmcnt(0)" ::: "memory");
    } else {
        asm volatile("s_waitcnt vmcnt(0) lgkmcnt(0)" ::: "memory");
    }
    __builtin_amdgcn_sched_barrier(0);
    __builtin_amdgcn_s_barrier();
    __builtin_amdgcn_sched_barrier(0);

    for (int t = 0; t < nt; ++t) {
        char* AH = abase + (t & 1) * 8192;
        char* BH = bbase + (t % 3) * 8192;
        // issue next-A (reg or gl_lds) and next-next-B
        if (A32) {
            if (t + 1 < nt) a32_load(Af32, K, bm, M - 1, tid, (t + 1) * 32, pre);
        } else if (t + 1 < nt) {
            stage_plane32(Af + (t + 1) * 32, K, bm, M - 1,
                          abase + ((t + 1) & 1) * 8192, tid);
        }
        if (t + 2 < nt)
            stage_plane32(Bt + (t + 2) * 32, K, bn, NCOL - 1,
                          bbase + ((t + 2) % 3) * 8192, tid);
        f16x8_t fa[4], fb[4];
#pragma unroll
        for (int mf = 0; mf < 4; ++mf) {
            int row = wm * 64 + mf * 16 + l15;
            fa[mf] = *(const f16x8_t*)(AH + row * 64 + ((l4 ^ swz) << 4));
        }
#pragma unroll
        for (int nf = 0; nf < 4; ++nf) {
            int rn = wn * 64 + nf * 16 + l15;
            fb[nf] = *(const f16x8_t*)(BH + rn * 64 + ((l4 ^ swz) << 4));
        }
#pragma unroll
        for (int mf = 0; mf < 4; ++mf)
#pragma unroll
            for (int nf = 0; nf < 4; ++nf)
                acc[mf][nf] = __builtin_amdgcn_mfma_f32_16x16x32_f16(fa[mf], fb[nf], acc[mf][nf], 0, 0, 0);
        if (A32 && t + 1 < nt)
            a32_write(abase + ((t + 1) & 1) * 8192, tid, pre);
        // counted drain: leave only B(t+2)'s loads in flight across the barrier
        if (t + 2 < nt) asm volatile("s_waitcnt vmcnt(2) lgkmcnt(0)" ::: "memory");
        else            asm volatile("s_waitcnt vmcnt(0) lgkmcnt(0)" ::: "memory");
        __builtin_amdgcn_sched_barrier(0);
        __builtin_amdgcn_s_barrier();
        __builtin_amdgcn_sched_barrier(0);
    }
    // epilogue: C/D layout col=lane&15, row=(lane>>4)*4+reg
#pragma unroll
    for (int mf = 0; mf < 4; ++mf) {
        int rbase = bm + wm * 64 + mf * 16 + l4 * 4;
#pragma unroll
        for (int nf = 0; nf < 4; ++nf) {
            int col = bn + wn * 64 + nf * 16 + l15;
            if (col >= NCOL) continue;
#pragma unroll
            for (int r = 0; r < 4; ++r) {
                int row = rbase + r;
                if (row < M) {
                    float v = acc[mf][nf][r];
                    if (EPI) {
                        v += bias[col];
                        v = v > 0.f ? v : (expf(v) - 1.f);
                    }
                    if (OUT16) ((_Float16*)Cout)[(size_t)row * ldC + col] = (_Float16)v;
                    else       ((float*)Cout)[(size_t)row * ldC + col] = v;
                }
            }
        }
    }
    if (ELER) {
        const int head = bcol;                 // 128-col tile == one head
        float alv[4], arv[4];
#pragma unroll
        for (int nf = 0; nf < 4; ++nf) {
            int cl = wn * 64 + nf * 16 + l15;  // col within head (0..127)
            alv[nf] = attl[head * OUTF + cl];
            arv[nf] = attr[head * OUTF + cl];
        }
        float pel[4][4], perr[4][4];
#pragma unroll
        for (int mf = 0; mf < 4; ++mf)
#pragma unroll
            for (int r = 0; r < 4; ++r) {
                float se = 0.f, sr = 0.f;
#pragma unroll
                for (int nf = 0; nf < 4; ++nf) {
                    se = fmaf(acc[mf][nf][r], alv[nf], se);
                    sr = fmaf(acc[mf][nf][r], arv[nf], sr);
                }
                pel[mf][r] = se; perr[mf][r] = sr;
            }
        // reduce across the 16-lane column group
#pragma unroll
        for (int off = 1; off < 16; off <<= 1)
#pragma unroll
            for (int mf = 0; mf < 4; ++mf)
#pragma unroll
                for (int r = 0; r < 4; ++r) {
                    pel[mf][r]  += __shfl_xor(pel[mf][r],  off);
                    perr[mf][r] += __shfl_xor(perr[mf][r], off);
                }
        __syncthreads();
        float* red = (float*)lds;              // [128][2] el, then [128][2] er
        if (l15 == 0) {
#pragma unroll
            for (int mf = 0; mf < 4; ++mf)
#pragma unroll
                for (int r = 0; r < 4; ++r) {
                    int rl = wm * 64 + mf * 16 + l4 * 4 + r;
                    red[rl * 2 + wn]       = pel[mf][r];
                    red[256 + rl * 2 + wn] = perr[mf][r];
                }
        }
        __syncthreads();
        if (tid < 128) {
            int row = bm + tid;
            if (row < M) {
                float es = red[tid * 2] + red[tid * 2 + 1];
                float rs = red[256 + tid * 2] + red[256 + tid * 2 + 1];
                elp[row * HEADS + head] = es;
                erp[row * HEADS + head] = rs;
            }
        }
    }
}

// --------------------------- CSR build -------------------------------------
__global__ void hist_kernel(const int* __restrict__ dst, int* __restrict__ deg, int E)
{
    int e = blockIdx.x * 256 + threadIdx.x;
    if (e < E) atomicAdd(&deg[dst[e]], 1);
}

__global__ __launch_bounds__(256) void scan1_kernel(const int* __restrict__ deg,
    int* __restrict__ offs, int* __restrict__ bsum, int N)
{
    __shared__ int buf[256];
    int tid = threadIdx.x;
    int i = blockIdx.x * 256 + tid;
    int v = (i < N) ? deg[i] : 0;
    buf[tid] = v;
    __syncthreads();
#pragma unroll
    for (int off = 1; off < 256; off <<= 1) {
        int t = (tid >= off) ? buf[tid - off] : 0;
        __syncthreads();
        buf[tid] += t;
        __syncthreads();
    }
    if (i < N) offs[i] = buf[tid] - v;
    if (tid == 255) bsum[blockIdx.x] = buf[255];
}

__global__ void scan2_kernel(int* __restrict__ bsum, int nb)
{
    if (threadIdx.x == 0) {
        int acc = 0;
        for (int b = 0; b < nb; ++b) { int t = bsum[b]; bsum[b] = acc; acc += t; }
        bsum[nb] = acc;
    }
}

__global__ void scan3_kernel(int* __restrict__ offs, const int* __restrict__ bsum,
                             int N, int nb)
{
    int i = blockIdx.x * 256 + threadIdx.x;
    if (i < N) offs[i] += bsum[blockIdx.x];
    if (i == 0) offs[N] = bsum[nb];
}

// fill: write src-id directly into the node's slot (psrc = src[csr[...]])
__global__ void fill_kernel(const int* __restrict__ srcv, const int* __restrict__ dstv,
    const int* __restrict__ offs, int* __restrict__ cursor,
    int* __restrict__ psrc, int E)
{
    int e = blockIdx.x * 256 + threadIdx.x;
    if (e < E) {
        int d = dstv[e];
        int p = atomicAdd(&cursor[d], 1);
        psrc[offs[d] + p] = srcv[e];
    }
}

// ------ aggregation v5: barrier-free shuffle-broadcast, 4 nodes/block ------
// One wave per node (4 waves / 256-thr block). Chunk = 32 edges staged in
// registers: lane L stages edge (L&31) for head-pair (L>>5) -- one float2 el
// gather + 2 exp. Weights and source ids broadcast via __shfl (wave lockstep
// => no LDS, no __syncthreads). BW-bound at the gather delivery ceiling.
__global__ __launch_bounds__(256) void aggregate_kernel(const _Float16* __restrict__ h,
    const int* __restrict__ offs, const int* __restrict__ psrc,
    const float* __restrict__ el, const float* __restrict__ er,
    const float* __restrict__ bias, _Float16* __restrict__ xo, int N)
{
    const int n = blockIdx.x * 4 + (threadIdx.x >> 6);
    if (n >= N) return;
    const int lane = threadIdx.x & 63;
    const int c = lane * 8;
    const int head = lane >> 4;           // reader head (0..3)
    const int hp = lane >> 5;             // staged head-pair (0:h01, 1:h23)
    const int e31 = lane & 31;
    const int sbase = (head >> 1) << 5;   // source-lane base for my head-pair
    const int hsel = head & 1;

    const float2 er2 = *(const float2*)&er[n * HEADS + hp * 2];

    float acc[8];
#pragma unroll
    for (int k = 0; k < 8; ++k) acc[k] = 0.f;
    float ws = 0.f;

    const int beg = offs[n], end = offs[n + 1];
    for (int base = beg; base < end; base += 32) {
        const int cnt = min(32, end - base);
        int idx = base + e31;
        if (e31 >= cnt) idx = beg;        // safe dummy (deg >= 1: self loop)
        const int s = psrc[idx];
        const float2 lv = *(const float2*)&el[s * HEADS + hp * 2];
        float x0 = lv.x + er2.x; x0 = x0 > 0.f ? x0 : 0.2f * x0;
        float x1 = lv.y + er2.y; x1 = x1 > 0.f ? x1 : 0.2f * x1;
        const float wa = expf(x0);        // weight for head hp*2
        const float wb = expf(x1);        // weight for head hp*2+1

        int j = 0;
        for (; j + 4 <= cnt; j += 4) {
            int s0 = __shfl(s, j);     int s1 = __shfl(s, j + 1);
            int s2 = __shfl(s, j + 2); int s3 = __shfl(s, j + 3);
            float a0 = __shfl(wa, sbase + j),     b0 = __shfl(wb, sbase + j);
            float a1 = __shfl(wa, sbase + j + 1), b1 = __shfl(wb, sbase + j + 1);
            float a2 = __shfl(wa, sbase + j + 2), b2 = __shfl(wb, sbase + j + 2);
            float a3 = __shfl(wa, sbase + j + 3), b3 = __shfl(wb, sbase + j + 3);
            float w0 = hsel ? b0 : a0;
            float w1 = hsel ? b1 : a1;
            float w2 = hsel ? b2 : a2;
            float w3 = hsel ? b3 : a3;
            f16x8_t v0 = *(const f16x8_t*)&h[(size_t)s0 * HID + c];
            f16x8_t v1 = *(const f16x8_t*)&h[(size_t)s1 * HID + c];
            f16x8_t v2 = *(const f16x8_t*)&h[(size_t)s2 * HID + c];
            f16x8_t v3 = *(const f16x8_t*)&h[(size_t)s3 * HID + c];
#pragma unroll
            for (int k = 0; k < 8; ++k) {
                acc[k] = fmaf(w0, (float)v0[k], acc[k]);
                acc[k] = fmaf(w1, (float)v1[k], acc[k]);
                acc[k] = fmaf(w2, (float)v2[k], acc[k]);
                acc[k] = fmaf(w3, (float)v3[k], acc[k]);
            }
            ws += w0 + w1 + w2 + w3;
        }
        for (; j < cnt; ++j) {
            int s0 = __shfl(s, j);
            float a0 = __shfl(wa, sbase + j), b0 = __shfl(wb, sbase + j);
            float w0 = hsel ? b0 : a0;
            f16x8_t v0 = *(const f16x8_t*)&h[(size_t)s0 * HID + c];
#pragma unroll
            for (int k = 0; k < 8; ++k) acc[k] = fmaf(w0, (float)v0[k], acc[k]);
            ws += w0;
        }
    }
    float inv = 1.f / ws;
    float4 b0v = *(const float4*)&bias[c];
    float4 b1v = *(const float4*)&bias[c + 4];
    float bb[8] = {b0v.x, b0v.y, b0v.z, b0v.w, b1v.x, b1v.y, b1v.z, b1v.w};
    f16x8_t ov;
#pragma unroll
    for (int k = 0; k < 8; ++k) {
        float r = acc[k] * inv + bb[k];
        r = r > 0.f ? r : (expf(r) - 1.f);
        ov[k] = (_Float16)r;
    }
    *(f16x8_t*)&xo[(size_t)n * HID + c] = ov;
}

// ---------------------------------------------------------------------------
extern "C" void kernel_launch(void* const* d_in, const int* in_sizes, int n_in,
                              void* d_out, int out_size, void* d_ws, size_t ws_size,
                              hipStream_t stream)
{
    const float* feature = (const float*)d_in[0];
    const float* W1  = (const float*)d_in[1];
    const float* al1 = (const float*)d_in[2];
    const float* ar1 = (const float*)d_in[3];
    const float* b1  = (const float*)d_in[4];
    const float* W2  = (const float*)d_in[5];
    const float* al2 = (const float*)d_in[6];
    const float* ar2 = (const float*)d_in[7];
    const float* b2  = (const float*)d_in[8];
    const float* Wfc = (const float*)d_in[9];
    const float* bfc = (const float*)d_in[10];
    const int* src = (const int*)d_in[11];
    const int* dst = (const int*)d_in[12];
    const int N = in_sizes[0] / 1280;
    const int E = in_sizes[11];
    const int nb = (N + 255) / 256;
    float* out = (float*)d_out;

    char* ws = (char*)d_ws;
    size_t off = 0;
    auto alloc = [&](size_t bytes) {
        void* p = ws + off;
        off += (bytes + 255) & ~(size_t)255;
        return p;
    };
    int* deg    = (int*)alloc((size_t)N * 4);
    int* cursor = (int*)alloc((size_t)N * 4);
    int* offs   = (int*)alloc((size_t)(N + 1) * 4);
    int* bsum   = (int*)alloc((size_t)(nb + 1) * 4);
    float* el   = (float*)alloc((size_t)N * HEADS * 4);
    float* er   = (float*)alloc((size_t)N * HEADS * 4);
    int* psrc   = (int*)alloc((size_t)E * 4);
    _Float16* hbuf  = (_Float16*)alloc((size_t)N * HID * 2);
    _Float16* xh    = (_Float16*)alloc((size_t)N * HID * 2);
    _Float16* W1t   = (_Float16*)alloc((size_t)HID * 1280 * 2);
    _Float16* W2t   = (_Float16*)alloc((size_t)HID * HID * 2);
    _Float16* Wft   = (_Float16*)alloc((size_t)64 * HID * 2);

    // CSR build (psrc written directly)
    hipMemsetAsync(deg, 0, (size_t)N * 4, stream);
    hipMemsetAsync(cursor, 0, (size_t)N * 4, stream);
    hist_kernel<<<(E + 255) / 256, 256, 0, stream>>>(dst, deg, E);
    scan1_kernel<<<nb, 256, 0, stream>>>(deg, offs, bsum, N);
    scan2_kernel<<<1, 64, 0, stream>>>(bsum, nb);
    scan3_kernel<<<nb, 256, 0, stream>>>(offs, bsum, N, nb);
    fill_kernel<<<(E + 255) / 256, 256, 0, stream>>>(src, dst, offs, cursor, psrc, E);

    // W prep (fp16, transposed). conv16 stays fused into the L1 GEMM (A32=1).
    prep_w<<<dim3(1280 / 32, HID / 32), 256, 0, stream>>>(W1, W1t, 1280, HID);
    prep_w<<<dim3(HID / 32, HID / 32), 256, 0, stream>>>(W2, W2t, HID, HID);
    prep_w<<<dim3(HID / 32, 64 / 32), 256, 0, stream>>>(Wfc, Wft, HID, 64);

    const int nrowT = (N + 127) / 128;
    const int nwgG = nrowT * 4;             // 4 col tiles of 128
    const int nwgF = nrowT;                 // 1 col tile (NCOL=64)
    const int aggB = (N + 3) / 4;

    // ---- layer 1 (GEMM on fp32 feature + fused el/er) ----
    gemm_f16<0, 1, 1, 1><<<nwgG, 256, 0, stream>>>(feature, W1t, nullptr,
                                                   al1, ar1, el, er,
                                                   hbuf, N, 1280, HID, HID,
                                                   4, nwgG);
    aggregate_kernel<<<aggB, 256, 0, stream>>>(hbuf, offs, psrc, el, er, b1, xh, N);

    // ---- layer 2 ----
    gemm_f16<0, 1, 1, 0><<<nwgG, 256, 0, stream>>>(xh, W2t, nullptr,
                                                   al2, ar2, el, er,
                                                   hbuf, N, HID, HID, HID,
                                                   4, nwgG);
    aggregate_kernel<<<aggB, 256, 0, stream>>>(hbuf, offs, psrc, el, er, b2, xh, N);

    // ---- fc: MFMA GEMM with fused bias+ELU, fp32 out ----
    gemm_f16<1, 0, 0, 0><<<nwgF, 256, 0, stream>>>(xh, Wft, bfc,
                                                   nullptr, nullptr, nullptr, nullptr,
                                                   out, N, HID, 64, 64,
                                                   1, nwgF);
}